// Round 1
// baseline (277.726 us; speedup 1.0000x reference)
//
#include <hip/hip_runtime.h>
#include <hip/hip_bf16.h>
#include <math.h>

typedef float f32x4 __attribute__((ext_vector_type(4)));
typedef short bf16x8_t __attribute__((ext_vector_type(8)));
typedef unsigned short u16;

#define SEQ     2048
#define DMODEL  1024
#define HEADS   16
#define DK      64

__device__ __forceinline__ u16 f2bf(float f) {
    union { float f; unsigned int u; } x; x.f = f;
    unsigned int r = x.u + 0x7fffu + ((x.u >> 16) & 1u);
    return (u16)(r >> 16);
}

__device__ __forceinline__ void gload_lds16(const u16* g, u16* l) {
    __builtin_amdgcn_global_load_lds((const __attribute__((address_space(1))) void*)g,
                                     (__attribute__((address_space(3))) void*)l,
                                     16, 0, 0);
}

// ---------------------------------------------------------------------------
// fused fp32 -> bf16 conversion for x + 4 weights
// ---------------------------------------------------------------------------
__global__ void cvt5(const float* __restrict__ s0, const float* __restrict__ s1,
                     const float* __restrict__ s2, const float* __restrict__ s3,
                     const float* __restrict__ s4,
                     u16* __restrict__ d0, u16* __restrict__ d1, u16* __restrict__ d2,
                     u16* __restrict__ d3, u16* __restrict__ d4,
                     int n0, int n1, int n2, int n3, int n4)
{
    const float* s; u16* d; int n;
    switch (blockIdx.y) {
        case 0: s = s0; d = d0; n = n0; break;
        case 1: s = s1; d = d1; n = n1; break;
        case 2: s = s2; d = d2; n = n2; break;
        case 3: s = s3; d = d3; n = n3; break;
        default: s = s4; d = d4; n = n4; break;
    }
    int i = (blockIdx.x * 256 + threadIdx.x) * 4;
    if (i >= n) return;
    float4 v = *(const float4*)(s + i);
    ushort4 o;
    o.x = f2bf(v.x); o.y = f2bf(v.y); o.z = f2bf(v.z); o.w = f2bf(v.w);
    *(ushort4*)(d + i) = o;
}

// ---------------------------------------------------------------------------
// GEMM: C[m][n] = sum_k A[m][k] * B[n][k]   (both row-major, K contiguous)
// 128x128 tile, BK=64, 4 waves (each 64x64), global_load_lds width-16 staging.
// blockIdx.z selects one of up to 3 (B, C) pairs (fused QKV).
// ---------------------------------------------------------------------------
template<int OUTBF16>
__launch_bounds__(256, 2)
__global__ void gemm_bt(const u16* __restrict__ A,
                        const u16* __restrict__ B0, const u16* __restrict__ B1,
                        const u16* __restrict__ B2,
                        void* C0v, void* C1v, void* C2v,
                        int M, int N, int K)
{
    const u16* B = (blockIdx.z == 0) ? B0 : (blockIdx.z == 1 ? B1 : B2);
    void* Cv     = (blockIdx.z == 0) ? C0v : (blockIdx.z == 1 ? C1v : C2v);

    __shared__ u16 Als[128 * 64];
    __shared__ u16 Bls[128 * 64];

    const int tid = threadIdx.x;
    const int w = tid >> 6, l = tid & 63;
    const int rl = l & 15, rh = l >> 4;
    const int row0 = blockIdx.x * 128, col0 = blockIdx.y * 128;
    const int wr = (w >> 1) * 64, wc = (w & 1) * 64;

    f32x4 acc[4][4];
    #pragma unroll
    for (int i = 0; i < 4; i++)
        #pragma unroll
        for (int j = 0; j < 4; j++)
            acc[i][j] = (f32x4){0.f, 0.f, 0.f, 0.f};

    for (int kt = 0; kt < K; kt += 64) {
        #pragma unroll
        for (int i = 0; i < 4; i++) {
            int c = i * 256 + tid;          // chunk id 0..1023
            int r = c >> 3, s = c & 7;      // row 0..127, 16B-seg 0..7
            gload_lds16(A + (size_t)(row0 + r) * K + kt + s * 8, &Als[(i * 256 + w * 64) * 8]);
            gload_lds16(B + (size_t)(col0 + r) * K + kt + s * 8, &Bls[(i * 256 + w * 64) * 8]);
        }
        __syncthreads();

        bf16x8_t af[4][2], bfr[4][2];
        #pragma unroll
        for (int mi = 0; mi < 4; mi++)
            #pragma unroll
            for (int k0 = 0; k0 < 2; k0++)
                af[mi][k0] = *(const bf16x8_t*)&Als[(wr + mi * 16 + rl) * 64 + k0 * 32 + rh * 8];
        #pragma unroll
        for (int ni = 0; ni < 4; ni++)
            #pragma unroll
            for (int k0 = 0; k0 < 2; k0++)
                bfr[ni][k0] = *(const bf16x8_t*)&Bls[(wc + ni * 16 + rl) * 64 + k0 * 32 + rh * 8];

        #pragma unroll
        for (int mi = 0; mi < 4; mi++)
            #pragma unroll
            for (int ni = 0; ni < 4; ni++)
                #pragma unroll
                for (int k0 = 0; k0 < 2; k0++)
                    acc[mi][ni] = __builtin_amdgcn_mfma_f32_16x16x32_bf16(
                        af[mi][k0], bfr[ni][k0], acc[mi][ni], 0, 0, 0);
        __syncthreads();
    }

    #pragma unroll
    for (int mi = 0; mi < 4; mi++)
        #pragma unroll
        for (int ni = 0; ni < 4; ni++) {
            int r = row0 + wr + mi * 16 + rh * 4;
            int c = col0 + wc + ni * 16 + rl;
            #pragma unroll
            for (int j = 0; j < 4; j++) {
                if (OUTBF16) ((u16*)Cv)[(size_t)(r + j) * N + c] = f2bf(acc[mi][ni][j]);
                else         ((float*)Cv)[(size_t)(r + j) * N + c] = acc[mi][ni][j];
            }
        }
}

// ---------------------------------------------------------------------------
// Causal flash attention. grid = (16 q-tiles, 32 b*h). 4 waves x 32 q-rows.
// K-tiles of 64. dk = 64.
// ---------------------------------------------------------------------------
__launch_bounds__(256, 2)
__global__ void attn_fwd(const u16* __restrict__ Q, const u16* __restrict__ Kp,
                         const u16* __restrict__ Vp, u16* __restrict__ O)
{
    const int qt = blockIdx.x;
    const int bh = blockIdx.y;
    const int b = bh >> 4, h = bh & 15;
    const int tid = threadIdx.x, w = tid >> 6, l = tid & 63;
    const int rl = l & 15, rh = l >> 4;

    __shared__ u16 Kls[64 * 64];
    __shared__ u16 Vt[64 * 64];
    __shared__ u16 Pls[4][32 * 64];

    const size_t base = (size_t)b * SEQ * DMODEL + h * DK;

    // Q fragments in registers (wave w owns q-rows qt*128 + w*32 .. +31)
    bf16x8_t qf[2][2];
    #pragma unroll
    for (int mi = 0; mi < 2; mi++)
        #pragma unroll
        for (int k0 = 0; k0 < 2; k0++) {
            int row = qt * 128 + w * 32 + mi * 16 + rl;
            qf[mi][k0] = *(const bf16x8_t*)(Q + base + (size_t)row * DMODEL + k0 * 32 + rh * 8);
        }

    f32x4 o_acc[2][4];
    float m_run[2][4], l_run[2][4];
    #pragma unroll
    for (int mi = 0; mi < 2; mi++) {
        #pragma unroll
        for (int nd = 0; nd < 4; nd++) o_acc[mi][nd] = (f32x4){0.f, 0.f, 0.f, 0.f};
        #pragma unroll
        for (int j = 0; j < 4; j++) { m_run[mi][j] = -INFINITY; l_run[mi][j] = 0.f; }
    }

    const int tmax = 2 * qt + 1;
    for (int t = 0; t <= tmax; t++) {
        // stage K tile [64 kv][64 d] and V^T tile [64 d][64 kv]
        {
            int r = tid >> 2, s5 = (tid & 3) * 16;
            const u16* kg = Kp + base + (size_t)(t * 64 + r) * DMODEL + s5;
            bf16x8_t k0v = *(const bf16x8_t*)kg;
            bf16x8_t k1v = *(const bf16x8_t*)(kg + 8);
            *(bf16x8_t*)&Kls[r * 64 + s5]     = k0v;
            *(bf16x8_t*)&Kls[r * 64 + s5 + 8] = k1v;
            const u16* vg = Vp + base + (size_t)(t * 64 + r) * DMODEL + s5;
            bf16x8_t v0v = *(const bf16x8_t*)vg;
            bf16x8_t v1v = *(const bf16x8_t*)(vg + 8);
            #pragma unroll
            for (int j = 0; j < 8; j++) {
                Vt[(s5 + j) * 64 + r]     = (u16)v0v[j];
                Vt[(s5 + 8 + j) * 64 + r] = (u16)v1v[j];
            }
        }
        __syncthreads();

        // S = Q K^T
        f32x4 sa[2][4];
        #pragma unroll
        for (int mi = 0; mi < 2; mi++)
            #pragma unroll
            for (int ni = 0; ni < 4; ni++) sa[mi][ni] = (f32x4){0.f, 0.f, 0.f, 0.f};
        #pragma unroll
        for (int k0 = 0; k0 < 2; k0++) {
            bf16x8_t kf[4];
            #pragma unroll
            for (int ni = 0; ni < 4; ni++)
                kf[ni] = *(const bf16x8_t*)&Kls[(ni * 16 + rl) * 64 + k0 * 32 + rh * 8];
            #pragma unroll
            for (int mi = 0; mi < 2; mi++)
                #pragma unroll
                for (int ni = 0; ni < 4; ni++)
                    sa[mi][ni] = __builtin_amdgcn_mfma_f32_16x16x32_bf16(
                        qf[mi][k0], kf[ni], sa[mi][ni], 0, 0, 0);
        }

        // scale + causal mask + online softmax
        #pragma unroll
        for (int mi = 0; mi < 2; mi++) {
            float rmax[4], rsum[4];
            #pragma unroll
            for (int j = 0; j < 4; j++) {
                const int qrow = qt * 128 + w * 32 + mi * 16 + rh * 4 + j;
                float mx = -INFINITY;
                #pragma unroll
                for (int ni = 0; ni < 4; ni++) {
                    float s = sa[mi][ni][j] * 0.125f;
                    const int kvcol = t * 64 + ni * 16 + rl;
                    s = (kvcol > qrow) ? -INFINITY : s;
                    sa[mi][ni][j] = s;
                    mx = fmaxf(mx, s);
                }
                rmax[j] = mx;
            }
            #pragma unroll
            for (int msk = 1; msk < 16; msk <<= 1)
                #pragma unroll
                for (int j = 0; j < 4; j++)
                    rmax[j] = fmaxf(rmax[j], __shfl_xor(rmax[j], msk, 64));
            #pragma unroll
            for (int j = 0; j < 4; j++) {
                const float mn = fmaxf(m_run[mi][j], rmax[j]);
                const float alpha = __expf(m_run[mi][j] - mn);
                m_run[mi][j] = mn;
                float rs = 0.f;
                #pragma unroll
                for (int ni = 0; ni < 4; ni++) {
                    float p = __expf(sa[mi][ni][j] - mn);
                    sa[mi][ni][j] = p;
                    rs += p;
                }
                rsum[j] = rs;
                l_run[mi][j] *= alpha;
                #pragma unroll
                for (int nd = 0; nd < 4; nd++) o_acc[mi][nd][j] *= alpha;
            }
            #pragma unroll
            for (int msk = 1; msk < 16; msk <<= 1)
                #pragma unroll
                for (int j = 0; j < 4; j++)
                    rsum[j] += __shfl_xor(rsum[j], msk, 64);
            #pragma unroll
            for (int j = 0; j < 4; j++) l_run[mi][j] += rsum[j];
            // store P (bf16) to per-wave LDS: [local_row 0..31][kv_local 0..63]
            #pragma unroll
            for (int ni = 0; ni < 4; ni++)
                #pragma unroll
                for (int j = 0; j < 4; j++)
                    Pls[w][(mi * 16 + rh * 4 + j) * 64 + ni * 16 + rl] = f2bf(sa[mi][ni][j]);
        }

        // O += P V   (DS ops are in-order per wave; P written above by this wave)
        #pragma unroll
        for (int k0 = 0; k0 < 2; k0++) {
            bf16x8_t pf[2], vf[4];
            #pragma unroll
            for (int mi = 0; mi < 2; mi++)
                pf[mi] = *(const bf16x8_t*)&Pls[w][(mi * 16 + rl) * 64 + k0 * 32 + rh * 8];
            #pragma unroll
            for (int nd = 0; nd < 4; nd++)
                vf[nd] = *(const bf16x8_t*)&Vt[(nd * 16 + rl) * 64 + k0 * 32 + rh * 8];
            #pragma unroll
            for (int mi = 0; mi < 2; mi++)
                #pragma unroll
                for (int nd = 0; nd < 4; nd++)
                    o_acc[mi][nd] = __builtin_amdgcn_mfma_f32_16x16x32_bf16(
                        pf[mi], vf[nd], o_acc[mi][nd], 0, 0, 0);
        }
        __syncthreads();   // protect Kls/Vt before next tile's staging
    }

    // epilogue: O / l  -> global (bf16)
    #pragma unroll
    for (int mi = 0; mi < 2; mi++)
        #pragma unroll
        for (int nd = 0; nd < 4; nd++)
            #pragma unroll
            for (int j = 0; j < 4; j++) {
                int row = qt * 128 + w * 32 + mi * 16 + rh * 4 + j;
                O[base + (size_t)row * DMODEL + nd * 16 + rl] =
                    f2bf(o_acc[mi][nd][j] / l_run[mi][j]);
            }
}

// ---------------------------------------------------------------------------
extern "C" void kernel_launch(void* const* d_in, const int* in_sizes, int n_in,
                              void* d_out, int out_size, void* d_ws, size_t ws_size,
                              hipStream_t stream)
{
    const float* x  = (const float*)d_in[0];
    const float* wq = (const float*)d_in[1];
    const float* wk = (const float*)d_in[2];
    const float* wv = (const float*)d_in[3];
    const float* wo = (const float*)d_in[4];
    float* out = (float*)d_out;

    const size_t NX = (size_t)4096 * 1024;   // B*S*D
    const size_t NW = (size_t)1024 * 1024;

    u16* xb  = (u16*)d_ws;
    u16* wqb = xb  + NX;
    u16* wkb = wqb + NW;
    u16* wvb = wkb + NW;
    u16* wob = wvb + NW;
    u16* q   = wob + NW;
    u16* k   = q   + NX;
    u16* v   = k   + NX;
    u16* at  = v   + NX;

    cvt5<<<dim3(4096, 5), 256, 0, stream>>>(x, wq, wk, wv, wo,
                                            xb, wqb, wkb, wvb, wob,
                                            (int)NX, (int)NW, (int)NW, (int)NW, (int)NW);

    // Q/K/V projections: (4096x1024) @ (1024x1024)^T, fused over grid.z
    gemm_bt<1><<<dim3(32, 8, 3), 256, 0, stream>>>(xb, wqb, wkb, wvb,
                                                   q, k, v, 4096, 1024, 1024);

    attn_fwd<<<dim3(16, 32), 256, 0, stream>>>(q, k, v, at);

    // output projection -> fp32
    gemm_bt<0><<<dim3(32, 8, 1), 256, 0, stream>>>(at, wob, wob, wob,
                                                   out, out, out, 4096, 1024, 1024);
}

// Round 3
// 270.332 us; speedup vs baseline: 1.0274x; 1.0274x over previous
//
#include <hip/hip_runtime.h>
#include <hip/hip_bf16.h>
#include <math.h>

typedef float f32x4 __attribute__((ext_vector_type(4)));
typedef short bf16x8_t __attribute__((ext_vector_type(8)));
typedef unsigned short u16;
typedef unsigned int u32;

#define SEQ     2048
#define DMODEL  1024
#define HEADS   16
#define DK      64

__device__ __forceinline__ u16 f2bf(float f) {
    union { float f; unsigned int u; } x; x.f = f;
    unsigned int r = x.u + 0x7fffu + ((x.u >> 16) & 1u);
    return (u16)(r >> 16);
}

// XOR swizzle for 128B-row-stride LDS tiles: byte ^= ((row ^ row>>3) & 7) << 4
__device__ __forceinline__ int swz(int row) { return ((row ^ (row >> 3)) & 7) << 4; }

__device__ __forceinline__ void gload_lds16(const u16* g, u16* l) {
    __builtin_amdgcn_global_load_lds((const __attribute__((address_space(1))) void*)g,
                                     (__attribute__((address_space(3))) void*)l,
                                     16, 0, 0);
}

// ---------------------------------------------------------------------------
// fused fp32 -> bf16 conversion for x + 4 weights
// ---------------------------------------------------------------------------
__global__ void cvt5(const float* __restrict__ s0, const float* __restrict__ s1,
                     const float* __restrict__ s2, const float* __restrict__ s3,
                     const float* __restrict__ s4,
                     u16* __restrict__ d0, u16* __restrict__ d1, u16* __restrict__ d2,
                     u16* __restrict__ d3, u16* __restrict__ d4,
                     int n0, int n1, int n2, int n3, int n4)
{
    const float* s; u16* d; int n;
    switch (blockIdx.y) {
        case 0: s = s0; d = d0; n = n0; break;
        case 1: s = s1; d = d1; n = n1; break;
        case 2: s = s2; d = d2; n = n2; break;
        case 3: s = s3; d = d3; n = n3; break;
        default: s = s4; d = d4; n = n4; break;
    }
    int i = (blockIdx.x * 256 + threadIdx.x) * 4;
    if (i >= n) return;
    float4 v = *(const float4*)(s + i);
    ushort4 o;
    o.x = f2bf(v.x); o.y = f2bf(v.y); o.z = f2bf(v.z); o.w = f2bf(v.w);
    *(ushort4*)(d + i) = o;
}

// ---------------------------------------------------------------------------
// GEMM: C[m][n] = sum_k A[m][k] * B[n][k]  (row-major, K contiguous, BK=64)
// BM=128, BN template (128: 4 waves of 64x64; 64: 4 waves of 32x64).
// blockIdx.z selects one of up to 3 (B, C) pairs (fused QKV).
// ---------------------------------------------------------------------------
template<int OUTBF16, int BN>
__launch_bounds__(256, 2)
__global__ void gemm_bt(const u16* __restrict__ A,
                        const u16* __restrict__ B0, const u16* __restrict__ B1,
                        const u16* __restrict__ B2,
                        void* C0v, void* C1v, void* C2v,
                        int M, int N, int K)
{
    const u16* B = (blockIdx.z == 0) ? B0 : (blockIdx.z == 1 ? B1 : B2);
    void* Cv     = (blockIdx.z == 0) ? C0v : (blockIdx.z == 1 ? C1v : C2v);

    __shared__ u16 Als[128 * 64];
    __shared__ u16 Bls[BN * 64];

    const int tid = threadIdx.x;
    const int w = tid >> 6, l = tid & 63;
    const int rl = l & 15, rh = l >> 4;
    const int row0 = blockIdx.x * 128, col0 = blockIdx.y * BN;
    constexpr int MI = (BN == 128) ? 4 : 2;
    const int wr = (BN == 128) ? (w >> 1) * 64 : w * 32;
    const int wc = (BN == 128) ? (w & 1) * 64 : 0;

    f32x4 acc[MI][4];
    #pragma unroll
    for (int i = 0; i < MI; i++)
        #pragma unroll
        for (int j = 0; j < 4; j++)
            acc[i][j] = (f32x4){0.f, 0.f, 0.f, 0.f};

    for (int kt = 0; kt < K; kt += 64) {
        #pragma unroll
        for (int i = 0; i < 4; i++) {
            int c = i * 256 + tid;
            int r = c >> 3, s = c & 7;
            gload_lds16(A + (size_t)(row0 + r) * K + kt + s * 8, &Als[(i * 256 + w * 64) * 8]);
        }
        #pragma unroll
        for (int i = 0; i < BN / 32; i++) {
            int c = i * 256 + tid;
            int r = c >> 3, s = c & 7;
            gload_lds16(B + (size_t)(col0 + r) * K + kt + s * 8, &Bls[(i * 256 + w * 64) * 8]);
        }
        __syncthreads();

        bf16x8_t af[MI][2], bfr[4][2];
        #pragma unroll
        for (int mi = 0; mi < MI; mi++)
            #pragma unroll
            for (int k0 = 0; k0 < 2; k0++)
                af[mi][k0] = *(const bf16x8_t*)&Als[(wr + mi * 16 + rl) * 64 + k0 * 32 + rh * 8];
        #pragma unroll
        for (int ni = 0; ni < 4; ni++)
            #pragma unroll
            for (int k0 = 0; k0 < 2; k0++)
                bfr[ni][k0] = *(const bf16x8_t*)&Bls[(wc + ni * 16 + rl) * 64 + k0 * 32 + rh * 8];

        #pragma unroll
        for (int mi = 0; mi < MI; mi++)
            #pragma unroll
            for (int ni = 0; ni < 4; ni++)
                #pragma unroll
                for (int k0 = 0; k0 < 2; k0++)
                    acc[mi][ni] = __builtin_amdgcn_mfma_f32_16x16x32_bf16(
                        af[mi][k0], bfr[ni][k0], acc[mi][ni], 0, 0, 0);
        __syncthreads();
    }

    #pragma unroll
    for (int mi = 0; mi < MI; mi++)
        #pragma unroll
        for (int ni = 0; ni < 4; ni++) {
            int r = row0 + wr + mi * 16 + rh * 4;
            int c = col0 + wc + ni * 16 + rl;
            #pragma unroll
            for (int j = 0; j < 4; j++) {
                if (OUTBF16) ((u16*)Cv)[(size_t)(r + j) * N + c] = f2bf(acc[mi][ni][j]);
                else         ((float*)Cv)[(size_t)(r + j) * N + c] = acc[mi][ni][j];
            }
        }
}

// ---------------------------------------------------------------------------
// Causal flash attention. grid = (16 q-tiles big-first, 32 b*h).
// 4 waves x 32 q-rows. KV tiles of 64. dk = 64. All LDS XOR-swizzled.
// ---------------------------------------------------------------------------
__launch_bounds__(256, 2)
__global__ void attn_fwd(const u16* __restrict__ Q, const u16* __restrict__ Kp,
                         const u16* __restrict__ Vp, u16* __restrict__ O)
{
    const int qt = 15 - blockIdx.x;          // big-first for tail packing
    const int bh = blockIdx.y;
    const int b = bh >> 4, h = bh & 15;
    const int tid = threadIdx.x, w = tid >> 6, l = tid & 63;
    const int rl = l & 15, rh = l >> 4;

    __shared__ u16 Kls[64 * 64];
    __shared__ u16 Vt[64 * 64];              // V^T: rows = d, cols = kv
    __shared__ u16 Pls[4][32 * 64];

    const size_t base = (size_t)b * SEQ * DMODEL + h * DK;

    // Q fragments in registers (wave w owns q-rows qt*128 + w*32 .. +31)
    bf16x8_t qf[2][2];
    #pragma unroll
    for (int mi = 0; mi < 2; mi++)
        #pragma unroll
        for (int k0 = 0; k0 < 2; k0++) {
            int row = qt * 128 + w * 32 + mi * 16 + rl;
            qf[mi][k0] = *(const bf16x8_t*)(Q + base + (size_t)row * DMODEL + k0 * 32 + rh * 8);
        }

    f32x4 o_acc[2][4];
    float m_run[2][4], l_run[2][4];
    #pragma unroll
    for (int mi = 0; mi < 2; mi++) {
        #pragma unroll
        for (int nd = 0; nd < 4; nd++) o_acc[mi][nd] = (f32x4){0.f, 0.f, 0.f, 0.f};
        #pragma unroll
        for (int j = 0; j < 4; j++) { m_run[mi][j] = -INFINITY; l_run[mi][j] = 0.f; }
    }

    const float SC = 0.125f * 1.44269504f;   // 1/sqrt(dk) * log2(e)
    const int krl8 = l >> 3, ks = l & 7;     // K staging: row-in-8, 16B seg
    const int rpair = tid >> 3, dseg = tid & 7;  // V staging

    const int tmax = 2 * qt + 1;
    for (int t = 0; t <= tmax; t++) {
        // --- stage K via global_load_lds (pre-swizzled source, linear LDS) ---
        #pragma unroll
        for (int c = 0; c < 2; c++) {
            int kr = w * 16 + c * 8 + krl8;
            int sseg = ks ^ ((kr ^ (kr >> 3)) & 7);
            gload_lds16(Kp + base + (size_t)(t * 64 + kr) * DMODEL + sseg * 8,
                        &Kls[(w * 16 + c * 8) * 64]);
        }
        // --- stage V^T: reg load, packed b32 transposed swizzled writes ---
        {
            const u16* vg = Vp + base + (size_t)(t * 64 + 2 * rpair) * DMODEL + dseg * 8;
            bf16x8_t v0 = *(const bf16x8_t*)vg;
            bf16x8_t v1 = *(const bf16x8_t*)(vg + DMODEL);
            #pragma unroll
            for (int j = 0; j < 8; j++) {
                int d = dseg * 8 + j;
                u32 pk = (u32)(u16)v0[j] | ((u32)(u16)v1[j] << 16);
                *(u32*)((char*)Vt + ((d * 128 + rpair * 4) ^ swz(d))) = pk;
            }
        }
        __syncthreads();

        // --- S = Q K^T ---
        f32x4 sa[2][4];
        #pragma unroll
        for (int mi = 0; mi < 2; mi++)
            #pragma unroll
            for (int ni = 0; ni < 4; ni++) sa[mi][ni] = (f32x4){0.f, 0.f, 0.f, 0.f};
        #pragma unroll
        for (int k0 = 0; k0 < 2; k0++) {
            bf16x8_t kf[4];
            #pragma unroll
            for (int ni = 0; ni < 4; ni++) {
                int row = ni * 16 + rl;
                kf[ni] = *(const bf16x8_t*)((const char*)Kls +
                          (((row * 64 + k0 * 32 + rh * 8) * 2) ^ swz(row)));
            }
            #pragma unroll
            for (int mi = 0; mi < 2; mi++)
                #pragma unroll
                for (int ni = 0; ni < 4; ni++)
                    sa[mi][ni] = __builtin_amdgcn_mfma_f32_16x16x32_bf16(
                        qf[mi][k0], kf[ni], sa[mi][ni], 0, 0, 0);
        }

        // --- scale (log2 domain) + causal mask + online softmax ---
        const bool need_mask = (t >= 2 * qt);
        #pragma unroll
        for (int mi = 0; mi < 2; mi++) {
            float rmax[4], rsum[4];
            #pragma unroll
            for (int j = 0; j < 4; j++) {
                const int qrow = qt * 128 + w * 32 + mi * 16 + rh * 4 + j;
                float mx = -INFINITY;
                #pragma unroll
                for (int ni = 0; ni < 4; ni++) {
                    float s = sa[mi][ni][j] * SC;
                    if (need_mask) {
                        const int kvcol = t * 64 + ni * 16 + rl;
                        s = (kvcol > qrow) ? -INFINITY : s;
                    }
                    sa[mi][ni][j] = s;
                    mx = fmaxf(mx, s);
                }
                rmax[j] = mx;
            }
            #pragma unroll
            for (int msk = 1; msk < 16; msk <<= 1)
                #pragma unroll
                for (int j = 0; j < 4; j++)
                    rmax[j] = fmaxf(rmax[j], __shfl_xor(rmax[j], msk, 64));
            #pragma unroll
            for (int j = 0; j < 4; j++) {
                const float mn = fmaxf(m_run[mi][j], rmax[j]);
                const float alpha = exp2f(m_run[mi][j] - mn);
                m_run[mi][j] = mn;
                float rs = 0.f;
                #pragma unroll
                for (int ni = 0; ni < 4; ni++) {
                    float p = exp2f(sa[mi][ni][j] - mn);
                    sa[mi][ni][j] = p;
                    rs += p;
                }
                rsum[j] = rs;
                l_run[mi][j] *= alpha;
                #pragma unroll
                for (int nd = 0; nd < 4; nd++) o_acc[mi][nd][j] *= alpha;
            }
            #pragma unroll
            for (int msk = 1; msk < 16; msk <<= 1)
                #pragma unroll
                for (int j = 0; j < 4; j++)
                    rsum[j] += __shfl_xor(rsum[j], msk, 64);
            #pragma unroll
            for (int j = 0; j < 4; j++) l_run[mi][j] += rsum[j];
            // P (bf16) to per-wave LDS, swizzled scalar writes
            #pragma unroll
            for (int ni = 0; ni < 4; ni++)
                #pragma unroll
                for (int j = 0; j < 4; j++) {
                    int row = mi * 16 + rh * 4 + j;
                    *(u16*)((char*)&Pls[w][0] +
                            (((row * 64 + ni * 16 + rl) * 2) ^ swz(row))) = f2bf(sa[mi][ni][j]);
                }
        }

        // --- O += P V  (same-wave DS ordering; swizzled reads) ---
        #pragma unroll
        for (int k0 = 0; k0 < 2; k0++) {
            bf16x8_t pf[2], vf[4];
            #pragma unroll
            for (int mi = 0; mi < 2; mi++) {
                int row = mi * 16 + rl;
                pf[mi] = *(const bf16x8_t*)((const char*)&Pls[w][0] +
                          (((row * 64 + k0 * 32 + rh * 8) * 2) ^ swz(row)));
            }
            #pragma unroll
            for (int nd = 0; nd < 4; nd++) {
                int row = nd * 16 + rl;
                vf[nd] = *(const bf16x8_t*)((const char*)Vt +
                          (((row * 64 + k0 * 32 + rh * 8) * 2) ^ swz(row)));
            }
            #pragma unroll
            for (int mi = 0; mi < 2; mi++)
                #pragma unroll
                for (int nd = 0; nd < 4; nd++)
                    o_acc[mi][nd] = __builtin_amdgcn_mfma_f32_16x16x32_bf16(
                        pf[mi], vf[nd], o_acc[mi][nd], 0, 0, 0);
        }
        __syncthreads();
    }

    // epilogue: O / l -> global (bf16)
    #pragma unroll
    for (int mi = 0; mi < 2; mi++)
        #pragma unroll
        for (int nd = 0; nd < 4; nd++)
            #pragma unroll
            for (int j = 0; j < 4; j++) {
                int row = qt * 128 + w * 32 + mi * 16 + rh * 4 + j;
                O[base + (size_t)row * DMODEL + nd * 16 + rl] =
                    f2bf(o_acc[mi][nd][j] / l_run[mi][j]);
            }
}

// ---------------------------------------------------------------------------
extern "C" void kernel_launch(void* const* d_in, const int* in_sizes, int n_in,
                              void* d_out, int out_size, void* d_ws, size_t ws_size,
                              hipStream_t stream)
{
    const float* x  = (const float*)d_in[0];
    const float* wq = (const float*)d_in[1];
    const float* wk = (const float*)d_in[2];
    const float* wv = (const float*)d_in[3];
    const float* wo = (const float*)d_in[4];
    float* out = (float*)d_out;

    const size_t NX = (size_t)4096 * 1024;   // B*S*D
    const size_t NW = (size_t)1024 * 1024;

    u16* xb  = (u16*)d_ws;
    u16* wqb = xb  + NX;
    u16* wkb = wqb + NW;
    u16* wvb = wkb + NW;
    u16* wob = wvb + NW;
    u16* q   = wob + NW;
    u16* k   = q   + NX;
    u16* v   = k   + NX;
    u16* at  = v   + NX;

    cvt5<<<dim3(4096, 5), 256, 0, stream>>>(x, wq, wk, wv, wo,
                                            xb, wqb, wkb, wvb, wob,
                                            (int)NX, (int)NW, (int)NW, (int)NW, (int)NW);

    // Q/K/V projections: (4096x1024) @ (1024x1024)^T, fused over grid.z
    gemm_bt<1, 128><<<dim3(32, 8, 3), 256, 0, stream>>>(xb, wqb, wkb, wvb,
                                                        q, k, v, 4096, 1024, 1024);

    attn_fwd<<<dim3(16, 32), 256, 0, stream>>>(q, k, v, at);

    // output projection -> fp32 (BN=64 tile: 512 blocks = 2/CU)
    gemm_bt<0, 64><<<dim3(32, 16, 1), 256, 0, stream>>>(at, wob, wob, wob,
                                                        out, out, out, 4096, 1024, 1024);
}